// Round 7
// baseline (226.915 us; speedup 1.0000x reference)
//
#include <hip/hip_runtime.h>
#include <math.h>

#define B_ 8
#define S_ 1024
#define D_ 1024
constexpr int BS = B_ * S_;

typedef short bf16x8 __attribute__((ext_vector_type(8)));
typedef float f32x4 __attribute__((ext_vector_type(4)));

__device__ __forceinline__ unsigned short f2bf(float f) {
    unsigned int u = __float_as_uint(f);
    u += 0x7fffu + ((u >> 16) & 1u);
    return (unsigned short)(u >> 16);
}
__device__ __forceinline__ float bf2f(unsigned short h) {
    return __uint_as_float(((unsigned int)h) << 16);
}

__device__ __forceinline__ float block_reduce_sum(float val, float* sh) {
    int tid = threadIdx.x;
    int lane = tid & 63, w = tid >> 6;
    #pragma unroll
    for (int off = 32; off > 0; off >>= 1) val += __shfl_down(val, off, 64);
    if (lane == 0) sh[w] = val;
    __syncthreads();
    int nw = blockDim.x >> 6;
    float total = 0.f;
    for (int i = 0; i < nw; i++) total += sh[i];
    __syncthreads();
    return total;
}

// ---- LayerNorm (ddof=1, eps on std) -> bf16, + au = u.x, av = v.x ----------
__global__ void ln_kernel(const float* __restrict__ ctx,
                          const float* __restrict__ ln_a,
                          const float* __restrict__ ln_b,
                          const float* __restrict__ u,
                          const float* __restrict__ v,
                          unsigned short* __restrict__ xb,
                          float* __restrict__ au, float* __restrict__ av) {
    __shared__ float sh[4];
    int r = blockIdx.x;
    int tid = threadIdx.x;        // 256
    int d0 = tid * 4;
    const float* row = ctx + (size_t)r * D_;
    float4 x4 = *(const float4*)(row + d0);
    float s = x4.x + x4.y + x4.z + x4.w;
    float total = block_reduce_sum(s, sh);
    float mean = total * (1.0f / D_);
    float dx = x4.x - mean, dy = x4.y - mean, dz = x4.z - mean, dw = x4.w - mean;
    float sq = dx * dx + dy * dy + dz * dz + dw * dw;
    float varsum = block_reduce_sum(sq, sh);
    float var = varsum * (1.0f / (D_ - 1));
    float inv = 1.0f / (sqrtf(var) + 1e-6f);
    float4 a4 = *(const float4*)(ln_a + d0);
    float4 b4 = *(const float4*)(ln_b + d0);
    float y0 = a4.x * dx * inv + b4.x;
    float y1 = a4.y * dy * inv + b4.y;
    float y2 = a4.z * dz * inv + b4.z;
    float y3 = a4.w * dw * inv + b4.w;
    ushort4 o;
    o.x = f2bf(y0); o.y = f2bf(y1); o.z = f2bf(y2); o.w = f2bf(y3);
    *(ushort4*)(xb + (size_t)r * D_ + d0) = o;
    float4 u4 = *(const float4*)(u + d0);
    float4 v4 = *(const float4*)(v + d0);
    float pu = u4.x * y0 + u4.y * y1 + u4.z * y2 + u4.w * y3;
    float pv = v4.x * y0 + v4.y * y1 + v4.z * y2 + v4.w * y3;
    pu = block_reduce_sum(pu, sh);
    pv = block_reduce_sum(pv, sh);
    if (tid == 0) { au[r] = pu; av[r] = pv; }
}

// ---- prep: transpose-convert Wq,Wk -> bf16 AND bias terms ------------------
__global__ void prep_kernel(const float* __restrict__ Wq, const float* __restrict__ Wk,
                            const float* __restrict__ bq, const float* __restrict__ bk,
                            unsigned short* __restrict__ Wqt,
                            unsigned short* __restrict__ Wkt,
                            float* __restrict__ u, float* __restrict__ v,
                            float* __restrict__ c0) {
    int bid = blockIdx.x;
    int tid = threadIdx.x;         // 256
    if (bid < 2048) {
        __shared__ float t[32][33];
        const float* in = (bid < 1024) ? Wq : Wk;
        unsigned short* out = (bid < 1024) ? Wqt : Wkt;
        int bb = bid & 1023;
        int bx = (bb & 31) * 32, by = (bb >> 5) * 32;
        int tx = tid & 31, ty = tid >> 5;    // 32 x 8
        #pragma unroll
        for (int i = 0; i < 32; i += 8)
            t[ty + i][tx] = in[(size_t)(by + ty + i) * D_ + bx + tx];
        __syncthreads();
        #pragma unroll
        for (int i = 0; i < 32; i += 8)
            out[(size_t)(bx + ty + i) * D_ + by + tx] = f2bf(t[tx][ty + i]);
    } else {
        int b = bid - 2048;        // 8 blocks, 128 rows each
        float ua[4] = {}, va[4] = {};
        int d0 = b * 128;
        for (int d = d0; d < d0 + 128; d++) {
            float bqd = bq[d], bkd = bk[d];
            const float* wkr = Wk + (size_t)d * D_;
            const float* wqr = Wq + (size_t)d * D_;
            #pragma unroll
            for (int i = 0; i < 4; i++) {
                int c = tid + i * 256;
                ua[i] += wkr[c] * bqd;
                va[i] += wqr[c] * bkd;
            }
        }
        #pragma unroll
        for (int i = 0; i < 4; i++) {
            atomicAdd(&u[tid + i * 256], ua[i]);
            atomicAdd(&v[tid + i * 256], va[i]);
        }
        if (tid < 128) atomicAdd(c0, bq[d0 + tid] * bk[d0 + tid]);
    }
}

// ---- MFMA bf16 GEMM 64x64 tile: C = A * B^T (for Mt) -----------------------
__global__ __launch_bounds__(256) void gemm_bt64(
    const unsigned short* __restrict__ A,
    const unsigned short* __restrict__ Bt,
    unsigned short* __restrict__ C,
    int M, int N, int K) {
    __shared__ __align__(16) unsigned short As[64 * 64];
    __shared__ __align__(16) unsigned short Bs[64 * 64];
    const int tid = threadIdx.x;
    const int wave = tid >> 6, lane = tid & 63;
    const int bm = blockIdx.y * 64, bn = blockIdx.x * 64;
    const int lrow8 = lane >> 3;
    const int pchunk = lane & 7;
    const int m_lane = lane & 15, quad = lane >> 4;
    const int wr = wave >> 1, wc = wave & 1;

    f32x4 acc[2][2] = {};

    for (int k0 = 0; k0 < K; k0 += 64) {
        #pragma unroll
        for (int c = 0; c < 2; c++) {
            int row = wave * 16 + c * 8 + lrow8;
            int gchunk = pchunk ^ (row & 7);
            const unsigned short* gpA = A + (size_t)(bm + row) * K + k0 + gchunk * 8;
            const unsigned short* gpB = Bt + (size_t)(bn + row) * K + k0 + gchunk * 8;
            __builtin_amdgcn_global_load_lds(
                (const __attribute__((address_space(1))) void*)gpA,
                (__attribute__((address_space(3))) void*)(As + (wave * 16 + c * 8) * 64),
                16, 0, 0);
            __builtin_amdgcn_global_load_lds(
                (const __attribute__((address_space(1))) void*)gpB,
                (__attribute__((address_space(3))) void*)(Bs + (wave * 16 + c * 8) * 64),
                16, 0, 0);
        }
        __syncthreads();
        #pragma unroll
        for (int kk = 0; kk < 2; kk++) {
            bf16x8 af[2], bfr[2];
            #pragma unroll
            for (int i = 0; i < 2; i++) {
                int row = wr * 32 + i * 16 + m_lane;
                int lchunk = kk * 4 + quad;
                af[i] = *(const bf16x8*)(As + row * 64 + (lchunk ^ (row & 7)) * 8);
            }
            #pragma unroll
            for (int j = 0; j < 2; j++) {
                int row = wc * 32 + j * 16 + m_lane;
                int lchunk = kk * 4 + quad;
                bfr[j] = *(const bf16x8*)(Bs + row * 64 + (lchunk ^ (row & 7)) * 8);
            }
            #pragma unroll
            for (int i = 0; i < 2; i++)
                #pragma unroll
                for (int j = 0; j < 2; j++)
                    acc[i][j] = __builtin_amdgcn_mfma_f32_16x16x32_bf16(
                        af[i], bfr[j], acc[i][j], 0, 0, 0);
        }
        __syncthreads();
    }
    #pragma unroll
    for (int i = 0; i < 2; i++)
        #pragma unroll
        for (int j = 0; j < 2; j++)
            #pragma unroll
            for (int r = 0; r < 4; r++) {
                int row = bm + wr * 32 + i * 16 + quad * 4 + r;
                int col = bn + wc * 32 + j * 16 + m_lane;
                C[(size_t)row * N + col] = f2bf(acc[i][j][r]);
            }
}

// ---- MFMA GEMM 64x128 tile + fused banded dots (LDS-staged epilogue) -------
// Tile: 64 rows (M) x 128 cols (N), 4 waves each owning a 64x32 col stripe.
// Grid (N/128, M/64) = (8, 128) = 1024 blocks -> 4 blocks/CU.
__global__ __launch_bounds__(256) void gemm_fused(
    const unsigned short* __restrict__ A,   // Xb [BS][D]
    const unsigned short* __restrict__ Bt,  // Mt [D][D]
    float* __restrict__ ydu, float* __restrict__ ydd,
    int M, int N, int K) {
    __shared__ __align__(16) unsigned short smem[(64 + 128) * 64];  // 24 KB
    unsigned short* As = smem;              // [64][64]
    unsigned short* Bs = smem + 64 * 64;    // [128][64]
    const int tid = threadIdx.x;
    const int wave = tid >> 6, lane = tid & 63;
    const int bm = blockIdx.y * 64, bn = blockIdx.x * 128;
    const int lrow8 = lane >> 3;            // 0..7
    const int pchunk = lane & 7;
    const int m_lane = lane & 15, quad = lane >> 4;
    const int wc = wave;                    // wave owns cols wc*32..wc*32+31

    f32x4 acc[4][2] = {};                   // rows i*16, cols wc*32 + j*16

    for (int k0 = 0; k0 < K; k0 += 64) {
        // stage A: 64 rows, each wave 16 rows (2 issues of 8)
        #pragma unroll
        for (int c = 0; c < 2; c++) {
            int row = wave * 16 + c * 8 + lrow8;
            int gchunk = pchunk ^ (row & 7);
            const unsigned short* gpA = A + (size_t)(bm + row) * K + k0 + gchunk * 8;
            __builtin_amdgcn_global_load_lds(
                (const __attribute__((address_space(1))) void*)gpA,
                (__attribute__((address_space(3))) void*)(As + (wave * 16 + c * 8) * 64),
                16, 0, 0);
        }
        // stage B: 128 rows, each wave 32 rows (4 issues of 8)
        #pragma unroll
        for (int c = 0; c < 4; c++) {
            int row = wave * 32 + c * 8 + lrow8;
            int gchunk = pchunk ^ (row & 7);
            const unsigned short* gpB = Bt + (size_t)(bn + row) * K + k0 + gchunk * 8;
            __builtin_amdgcn_global_load_lds(
                (const __attribute__((address_space(1))) void*)gpB,
                (__attribute__((address_space(3))) void*)(Bs + (wave * 32 + c * 8) * 64),
                16, 0, 0);
        }
        __syncthreads();
        #pragma unroll
        for (int kk = 0; kk < 2; kk++) {
            bf16x8 af[4], bfr[2];
            #pragma unroll
            for (int i = 0; i < 4; i++) {
                int row = i * 16 + m_lane;
                int lchunk = kk * 4 + quad;
                af[i] = *(const bf16x8*)(As + row * 64 + (lchunk ^ (row & 7)) * 8);
            }
            #pragma unroll
            for (int j = 0; j < 2; j++) {
                int row = wc * 32 + j * 16 + m_lane;
                int lchunk = kk * 4 + quad;
                bfr[j] = *(const bf16x8*)(Bs + row * 64 + (lchunk ^ (row & 7)) * 8);
            }
            #pragma unroll
            for (int i = 0; i < 4; i++)
                #pragma unroll
                for (int j = 0; j < 2; j++)
                    acc[i][j] = __builtin_amdgcn_mfma_f32_16x16x32_bf16(
                        af[i], bfr[j], acc[i][j], 0, 0, 0);
        }
        __syncthreads();
    }

    // ---- epilogue: stage X tile [64][128] in LDS, stride 136 (bank-shift) --
    unsigned short* Xs = smem;              // [64][136] u16 = 17408 B
    #pragma unroll
    for (int it = 0; it < 4; it++) {
        int idx = it * 256 + tid;           // 16B-chunk id, 1024 total
        int lr = idx >> 4;                  // 0..63
        int ch = idx & 15;                  // 0..15
        *(bf16x8*)(Xs + lr * 136 + ch * 8) =
            *(const bf16x8*)(A + (size_t)(bm + lr) * K + bn + ch * 8);
    }
    __syncthreads();

    #pragma unroll
    for (int i = 0; i < 4; i++) {
        #pragma unroll
        for (int r = 0; r < 4; r++) {
            int lrow = i * 16 + quad * 4 + r;   // 0..63
            int row = bm + lrow;
            int s = row & (S_ - 1);
            bool hu = (s < S_ - 1), hd = (s > 0);
            float pu = 0.f, pd = 0.f;
            #pragma unroll
            for (int j = 0; j < 2; j++) {
                int lc = wc * 32 + j * 16 + m_lane;
                float a = acc[i][j][r];
                if (hu) {
                    float xu = (lrow < 63) ? bf2f(Xs[(lrow + 1) * 136 + lc])
                                           : bf2f(A[(size_t)(row + 1) * K + bn + lc]);
                    pu += a * xu;
                }
                if (hd) {
                    float xd = (lrow > 0) ? bf2f(Xs[(lrow - 1) * 136 + lc])
                                          : bf2f(A[(size_t)(row - 1) * K + bn + lc]);
                    pd += a * xd;
                }
            }
            #pragma unroll
            for (int off = 1; off < 16; off <<= 1) {
                pu += __shfl_xor(pu, off, 64);
                pd += __shfl_xor(pd, off, 64);
            }
            if (m_lane == 0) {
                atomicAdd(&ydu[row], pu);
                atomicAdd(&ydd[row], pd);
            }
        }
    }
}

// ---- fused banded softmax + f64 prefix scan --------------------------------
__global__ void softmax_prefix(const float* __restrict__ ydu, const float* __restrict__ ydd,
                               const float* __restrict__ au, const float* __restrict__ av,
                               const float* __restrict__ c0p, const int* __restrict__ eos,
                               float* __restrict__ Pup, float* __restrict__ Pdn,
                               float* __restrict__ bg, double* __restrict__ C) {
    __shared__ float pdsh[1024];
    __shared__ double wsum[16];
    int b = blockIdx.x;
    int t = threadIdx.x;           // 0..1023 = row s
    int r = b * S_ + t;
    float c0 = *c0p;
    const float inv_d = 1.0f / D_;
    bool mu = false, md = false;
    float su = 0.f, sd = 0.f;
    if (t < S_ - 1) {
        mu = eos[(size_t)b * S_ * S_ + (size_t)t * S_ + (t + 1)] != 0;
        su = (ydu[r] + av[r] + au[r + 1] + c0) * inv_d;
    }
    if (t > 0) {
        md = eos[(size_t)b * S_ * S_ + (size_t)t * S_ + (t - 1)] != 0;
        sd = (ydd[r] + av[r] + au[r - 1] + c0) * inv_d;
    }
    float pu, pd, pb;
    if (mu && md) {
        float m = fmaxf(su, sd);
        float eu = expf(su - m), ed = expf(sd - m);
        float inv = 1.0f / (eu + ed);
        pu = eu * inv; pd = ed * inv; pb = 0.f;
    } else if (mu) { pu = 1.f; pd = 0.f; pb = 0.f; }
    else if (md)   { pu = 0.f; pd = 1.f; pb = 0.f; }
    else           { pu = pd = pb = 1.0f / S_; }
    Pup[r] = pu; Pdn[r] = pd; bg[r] = pb;
    pdsh[t] = pd;
    __syncthreads();
    double l = 0.0;
    if (t < S_ - 1) {
        float p = sqrtf(pu * pdsh[t + 1] + 1e-9f) + 1e-9f;
        l = log((double)p);
    }
    int lane = t & 63, w = t >> 6;
    double vv = l;
    #pragma unroll
    for (int off = 1; off < 64; off <<= 1) {
        double o = __shfl_up(vv, off, 64);
        if (lane >= off) vv += o;
    }
    if (lane == 63) wsum[w] = vv;
    __syncthreads();
    if (t == 0) {
        double acc = 0.0;
        #pragma unroll
        for (int i = 0; i < 16; i++) { double x = wsum[i]; wsum[i] = acc; acc += x; }
    }
    __syncthreads();
    vv += wsum[w];
    size_t base = (size_t)b * S_;
    if (t == 0) C[base] = 0.0;
    if (t < S_ - 1) C[base + t + 1] = vv;
}

// ---- final outputs: g and neibor -------------------------------------------
__global__ void write_out(const float* __restrict__ Pup, const float* __restrict__ Pdn,
                          const float* __restrict__ bg, const double* __restrict__ C,
                          float* __restrict__ out) {
    int r = blockIdx.x;
    int b = r >> 10, s = r & (S_ - 1);
    size_t rowbase = (size_t)r * S_;
    size_t bb = (size_t)b * S_;
    float pu_s = (s < S_ - 1) ? Pup[r] : 0.f;
    float pd_s = (s > 0) ? Pdn[r] : 0.f;
    float bg_s = bg[r];
    double C_s = C[r];
    int t0 = threadIdx.x * 4;
    float* gp = out;
    float* np = out + (size_t)B_ * S_ * S_;
    float4 bgv = *(const float4*)(bg + bb + t0);
    float4 gv, nv;
    #pragma unroll
    for (int j = 0; j < 4; j++) {
        int t = t0 + j;
        float P_st = (t == s + 1) ? pu_s : ((t == s - 1) ? pd_s : bg_s);
        float P_ts;
        if (t == s - 1)      P_ts = Pup[bb + t];
        else if (t == s + 1) P_ts = Pdn[bb + t];
        else                 P_ts = ((const float*)&bgv)[j];
        float neib = sqrtf(P_st * P_ts + 1e-9f);
        float g;
        if (t == s) {
            g = neib;
        } else {
            double diff = (t > s) ? (C[bb + t] - C_s) : (C_s - C[bb + t]);
            g = expf((float)diff) + 1e-9f;
        }
        ((float*)&gv)[j] = g;
        ((float*)&nv)[j] = neib;
    }
    *(float4*)(gp + rowbase + t0) = gv;
    *(float4*)(np + rowbase + t0) = nv;
}

// ---- launcher ---------------------------------------------------------------
extern "C" void kernel_launch(void* const* d_in, const int* in_sizes, int n_in,
                              void* d_out, int out_size, void* d_ws, size_t ws_size,
                              hipStream_t stream) {
    const float* ctx  = (const float*)d_in[0];
    const int*   eos  = (const int*)d_in[1];
    const float* Wq   = (const float*)d_in[2];
    const float* bq   = (const float*)d_in[3];
    const float* Wk   = (const float*)d_in[4];
    const float* bk   = (const float*)d_in[5];
    const float* ln_a = (const float*)d_in[6];
    const float* ln_b = (const float*)d_in[7];
    float* out = (float*)d_out;

    char* ws = (char*)d_ws;
    size_t off = 0;
    auto alloc = [&](size_t bytes) {
        void* p = ws + off;
        off += (bytes + 255) & ~(size_t)255;
        return p;
    };
    unsigned short* Xb  = (unsigned short*)alloc((size_t)BS * D_ * 2);
    unsigned short* Wqt = (unsigned short*)alloc((size_t)D_ * D_ * 2);
    unsigned short* Wkt = (unsigned short*)alloc((size_t)D_ * D_ * 2);
    unsigned short* Mt  = (unsigned short*)alloc((size_t)D_ * D_ * 2);
    // ---- zeroed region (contiguous): ydu, ydd, u, v, c0 ----
    float*  ydu = (float*)alloc(BS * 4);
    float*  ydd = (float*)alloc(BS * 4);
    float*  u   = (float*)alloc(D_ * 4);
    float*  v   = (float*)alloc(D_ * 4);
    float*  c0  = (float*)alloc(4);
    size_t zero_bytes = (size_t)((char*)c0 - (char*)ydu) + 256;
    // ---- rest (written, not accumulated) ----
    float*  au  = (float*)alloc(BS * 4);
    float*  av  = (float*)alloc(BS * 4);
    float*  Pup = (float*)alloc(BS * 4);
    float*  Pdn = (float*)alloc(BS * 4);
    float*  bg  = (float*)alloc(BS * 4);
    double* Cp  = (double*)alloc(BS * 8);

    // 0. zero the atomic-accumulate targets
    hipMemsetAsync(ydu, 0, zero_bytes, stream);
    // 1. prep: transpose Wq/Wk -> bf16, bias terms u, v, c0
    prep_kernel<<<2056, 256, 0, stream>>>(Wq, Wk, bq, bk, Wqt, Wkt, u, v, c0);
    // 2. LayerNorm -> bf16 (+ au, av)
    ln_kernel<<<BS, 256, 0, stream>>>(ctx, ln_a, ln_b, u, v, Xb, au, av);
    // 3. Mt[n][k] = sum_d Wk[d][n] Wq[d][k]
    gemm_bt64<<<dim3(16, 16), 256, 0, stream>>>(Wkt, Wqt, Mt, D_, D_, D_);
    // 4. fused: Y = Xb Mt^T (registers only) + banded dots (LDS-staged)
    gemm_fused<<<dim3(8, 128), 256, 0, stream>>>(Xb, Mt, ydu, ydd, BS, D_, D_);
    // 5. fused banded softmax + prefix scan
    softmax_prefix<<<B_, 1024, 0, stream>>>(ydu, ydd, au, av, c0, eos, Pup, Pdn, bg, Cp);
    // 6. outputs
    write_out<<<BS, 256, 0, stream>>>(Pup, Pdn, bg, Cp, out);
}

// Round 8
// 215.053 us; speedup vs baseline: 1.0552x; 1.0552x over previous
//
#include <hip/hip_runtime.h>
#include <math.h>

#define B_ 8
#define S_ 1024
#define D_ 1024
constexpr int BS = B_ * S_;

typedef short bf16x8 __attribute__((ext_vector_type(8)));
typedef float f32x4 __attribute__((ext_vector_type(4)));

__device__ __forceinline__ unsigned short f2bf(float f) {
    unsigned int u = __float_as_uint(f);
    u += 0x7fffu + ((u >> 16) & 1u);
    return (unsigned short)(u >> 16);
}
__device__ __forceinline__ float bf2f(unsigned short h) {
    return __uint_as_float(((unsigned int)h) << 16);
}

__device__ __forceinline__ float block_reduce_sum(float val, float* sh) {
    int tid = threadIdx.x;
    int lane = tid & 63, w = tid >> 6;
    #pragma unroll
    for (int off = 32; off > 0; off >>= 1) val += __shfl_down(val, off, 64);
    if (lane == 0) sh[w] = val;
    __syncthreads();
    int nw = blockDim.x >> 6;
    float total = 0.f;
    for (int i = 0; i < nw; i++) total += sh[i];
    __syncthreads();
    return total;
}

// ---- LayerNorm (ddof=1, eps on std) -> bf16, + au = u.x, av = v.x ----------
__global__ void ln_kernel(const float* __restrict__ ctx,
                          const float* __restrict__ ln_a,
                          const float* __restrict__ ln_b,
                          const float* __restrict__ u,
                          const float* __restrict__ v,
                          unsigned short* __restrict__ xb,
                          float* __restrict__ au, float* __restrict__ av) {
    __shared__ float sh[4];
    int r = blockIdx.x;
    int tid = threadIdx.x;        // 256
    int d0 = tid * 4;
    const float* row = ctx + (size_t)r * D_;
    float4 x4 = *(const float4*)(row + d0);
    float s = x4.x + x4.y + x4.z + x4.w;
    float total = block_reduce_sum(s, sh);
    float mean = total * (1.0f / D_);
    float dx = x4.x - mean, dy = x4.y - mean, dz = x4.z - mean, dw = x4.w - mean;
    float sq = dx * dx + dy * dy + dz * dz + dw * dw;
    float varsum = block_reduce_sum(sq, sh);
    float var = varsum * (1.0f / (D_ - 1));
    float inv = 1.0f / (sqrtf(var) + 1e-6f);
    float4 a4 = *(const float4*)(ln_a + d0);
    float4 b4 = *(const float4*)(ln_b + d0);
    float y0 = a4.x * dx * inv + b4.x;
    float y1 = a4.y * dy * inv + b4.y;
    float y2 = a4.z * dz * inv + b4.z;
    float y3 = a4.w * dw * inv + b4.w;
    ushort4 o;
    o.x = f2bf(y0); o.y = f2bf(y1); o.z = f2bf(y2); o.w = f2bf(y3);
    *(ushort4*)(xb + (size_t)r * D_ + d0) = o;
    float4 u4 = *(const float4*)(u + d0);
    float4 v4 = *(const float4*)(v + d0);
    float pu = u4.x * y0 + u4.y * y1 + u4.z * y2 + u4.w * y3;
    float pv = v4.x * y0 + v4.y * y1 + v4.z * y2 + v4.w * y3;
    pu = block_reduce_sum(pu, sh);
    pv = block_reduce_sum(pv, sh);
    if (tid == 0) { au[r] = pu; av[r] = pv; }
}

// ---- prep: transpose-convert Wq,Wk -> bf16 AND bias terms ------------------
__global__ void prep_kernel(const float* __restrict__ Wq, const float* __restrict__ Wk,
                            const float* __restrict__ bq, const float* __restrict__ bk,
                            unsigned short* __restrict__ Wqt,
                            unsigned short* __restrict__ Wkt,
                            float* __restrict__ u, float* __restrict__ v,
                            float* __restrict__ c0) {
    int bid = blockIdx.x;
    int tid = threadIdx.x;         // 256
    if (bid < 2048) {
        __shared__ float t[32][33];
        const float* in = (bid < 1024) ? Wq : Wk;
        unsigned short* out = (bid < 1024) ? Wqt : Wkt;
        int bb = bid & 1023;
        int bx = (bb & 31) * 32, by = (bb >> 5) * 32;
        int tx = tid & 31, ty = tid >> 5;    // 32 x 8
        #pragma unroll
        for (int i = 0; i < 32; i += 8)
            t[ty + i][tx] = in[(size_t)(by + ty + i) * D_ + bx + tx];
        __syncthreads();
        #pragma unroll
        for (int i = 0; i < 32; i += 8)
            out[(size_t)(bx + ty + i) * D_ + by + tx] = f2bf(t[tx][ty + i]);
    } else {
        int b = bid - 2048;        // 8 blocks, 128 rows each
        float ua[4] = {}, va[4] = {};
        int d0 = b * 128;
        for (int d = d0; d < d0 + 128; d++) {
            float bqd = bq[d], bkd = bk[d];
            const float* wkr = Wk + (size_t)d * D_;
            const float* wqr = Wq + (size_t)d * D_;
            #pragma unroll
            for (int i = 0; i < 4; i++) {
                int c = tid + i * 256;
                ua[i] += wkr[c] * bqd;
                va[i] += wqr[c] * bkd;
            }
        }
        #pragma unroll
        for (int i = 0; i < 4; i++) {
            atomicAdd(&u[tid + i * 256], ua[i]);
            atomicAdd(&v[tid + i * 256], va[i]);
        }
        if (tid < 128) atomicAdd(c0, bq[d0 + tid] * bk[d0 + tid]);
    }
}

// ---- MFMA bf16 GEMM 64x64 tile: C = A * B^T (for Mt) -----------------------
__global__ __launch_bounds__(256) void gemm_bt64(
    const unsigned short* __restrict__ A,
    const unsigned short* __restrict__ Bt,
    unsigned short* __restrict__ C,
    int M, int N, int K) {
    __shared__ __align__(16) unsigned short As[64 * 64];
    __shared__ __align__(16) unsigned short Bs[64 * 64];
    const int tid = threadIdx.x;
    const int wave = tid >> 6, lane = tid & 63;
    const int bm = blockIdx.y * 64, bn = blockIdx.x * 64;
    const int lrow8 = lane >> 3;
    const int pchunk = lane & 7;
    const int m_lane = lane & 15, quad = lane >> 4;
    const int wr = wave >> 1, wc = wave & 1;

    f32x4 acc[2][2] = {};

    for (int k0 = 0; k0 < K; k0 += 64) {
        #pragma unroll
        for (int c = 0; c < 2; c++) {
            int row = wave * 16 + c * 8 + lrow8;
            int gchunk = pchunk ^ (row & 7);
            const unsigned short* gpA = A + (size_t)(bm + row) * K + k0 + gchunk * 8;
            const unsigned short* gpB = Bt + (size_t)(bn + row) * K + k0 + gchunk * 8;
            __builtin_amdgcn_global_load_lds(
                (const __attribute__((address_space(1))) void*)gpA,
                (__attribute__((address_space(3))) void*)(As + (wave * 16 + c * 8) * 64),
                16, 0, 0);
            __builtin_amdgcn_global_load_lds(
                (const __attribute__((address_space(1))) void*)gpB,
                (__attribute__((address_space(3))) void*)(Bs + (wave * 16 + c * 8) * 64),
                16, 0, 0);
        }
        __syncthreads();
        #pragma unroll
        for (int kk = 0; kk < 2; kk++) {
            bf16x8 af[2], bfr[2];
            #pragma unroll
            for (int i = 0; i < 2; i++) {
                int row = wr * 32 + i * 16 + m_lane;
                int lchunk = kk * 4 + quad;
                af[i] = *(const bf16x8*)(As + row * 64 + (lchunk ^ (row & 7)) * 8);
            }
            #pragma unroll
            for (int j = 0; j < 2; j++) {
                int row = wc * 32 + j * 16 + m_lane;
                int lchunk = kk * 4 + quad;
                bfr[j] = *(const bf16x8*)(Bs + row * 64 + (lchunk ^ (row & 7)) * 8);
            }
            #pragma unroll
            for (int i = 0; i < 2; i++)
                #pragma unroll
                for (int j = 0; j < 2; j++)
                    acc[i][j] = __builtin_amdgcn_mfma_f32_16x16x32_bf16(
                        af[i], bfr[j], acc[i][j], 0, 0, 0);
        }
        __syncthreads();
    }
    #pragma unroll
    for (int i = 0; i < 2; i++)
        #pragma unroll
        for (int j = 0; j < 2; j++)
            #pragma unroll
            for (int r = 0; r < 4; r++) {
                int row = bm + wr * 32 + i * 16 + quad * 4 + r;
                int col = bn + wc * 32 + j * 16 + m_lane;
                C[(size_t)row * N + col] = f2bf(acc[i][j][r]);
            }
}

// ---- MFMA GEMM 64x128 tile + fused banded dots, XCD-aware swizzle ----------
// Linear grid 1024: m_tile = bid & 127, n_tile = bid >> 7. The 8 blocks that
// share an m_tile have bid = m + 128n -> XCD (bid%8) = m%8: all on ONE XCD,
// so each A-row-tile is fetched into exactly one per-XCD L2.
__global__ __launch_bounds__(256) void gemm_fused(
    const unsigned short* __restrict__ A,   // Xb [BS][D]
    const unsigned short* __restrict__ Bt,  // Mt [D][D]
    float* __restrict__ ydu, float* __restrict__ ydd,
    int M, int N, int K) {
    __shared__ __align__(16) unsigned short smem[(64 + 128) * 64];  // 24 KB
    unsigned short* As = smem;              // [64][64]
    unsigned short* Bs = smem + 64 * 64;    // [128][64]
    const int tid = threadIdx.x;
    const int wave = tid >> 6, lane = tid & 63;
    const int bid = blockIdx.x;
    const int bm = (bid & 127) * 64, bn = (bid >> 7) * 128;
    const int lrow8 = lane >> 3;            // 0..7
    const int pchunk = lane & 7;
    const int m_lane = lane & 15, quad = lane >> 4;
    const int wc = wave;                    // wave owns cols wc*32..wc*32+31

    f32x4 acc[4][2] = {};                   // rows i*16, cols wc*32 + j*16

    for (int k0 = 0; k0 < K; k0 += 64) {
        // stage A: 64 rows, each wave 16 rows (2 issues of 8)
        #pragma unroll
        for (int c = 0; c < 2; c++) {
            int row = wave * 16 + c * 8 + lrow8;
            int gchunk = pchunk ^ (row & 7);
            const unsigned short* gpA = A + (size_t)(bm + row) * K + k0 + gchunk * 8;
            __builtin_amdgcn_global_load_lds(
                (const __attribute__((address_space(1))) void*)gpA,
                (__attribute__((address_space(3))) void*)(As + (wave * 16 + c * 8) * 64),
                16, 0, 0);
        }
        // stage B: 128 rows, each wave 32 rows (4 issues of 8)
        #pragma unroll
        for (int c = 0; c < 4; c++) {
            int row = wave * 32 + c * 8 + lrow8;
            int gchunk = pchunk ^ (row & 7);
            const unsigned short* gpB = Bt + (size_t)(bn + row) * K + k0 + gchunk * 8;
            __builtin_amdgcn_global_load_lds(
                (const __attribute__((address_space(1))) void*)gpB,
                (__attribute__((address_space(3))) void*)(Bs + (wave * 32 + c * 8) * 64),
                16, 0, 0);
        }
        __syncthreads();
        #pragma unroll
        for (int kk = 0; kk < 2; kk++) {
            bf16x8 af[4], bfr[2];
            #pragma unroll
            for (int i = 0; i < 4; i++) {
                int row = i * 16 + m_lane;
                int lchunk = kk * 4 + quad;
                af[i] = *(const bf16x8*)(As + row * 64 + (lchunk ^ (row & 7)) * 8);
            }
            #pragma unroll
            for (int j = 0; j < 2; j++) {
                int row = wc * 32 + j * 16 + m_lane;
                int lchunk = kk * 4 + quad;
                bfr[j] = *(const bf16x8*)(Bs + row * 64 + (lchunk ^ (row & 7)) * 8);
            }
            #pragma unroll
            for (int i = 0; i < 4; i++)
                #pragma unroll
                for (int j = 0; j < 2; j++)
                    acc[i][j] = __builtin_amdgcn_mfma_f32_16x16x32_bf16(
                        af[i], bfr[j], acc[i][j], 0, 0, 0);
        }
        __syncthreads();
    }

    // ---- epilogue: stage X tile [64][128] in LDS, stride 136 (bank-shift) --
    unsigned short* Xs = smem;              // [64][136] u16 = 17408 B
    #pragma unroll
    for (int it = 0; it < 4; it++) {
        int idx = it * 256 + tid;           // 16B-chunk id, 1024 total
        int lr = idx >> 4;                  // 0..63
        int ch = idx & 15;                  // 0..15
        *(bf16x8*)(Xs + lr * 136 + ch * 8) =
            *(const bf16x8*)(A + (size_t)(bm + lr) * K + bn + ch * 8);
    }
    __syncthreads();

    #pragma unroll
    for (int i = 0; i < 4; i++) {
        #pragma unroll
        for (int r = 0; r < 4; r++) {
            int lrow = i * 16 + quad * 4 + r;   // 0..63
            int row = bm + lrow;
            int s = row & (S_ - 1);
            bool hu = (s < S_ - 1), hd = (s > 0);
            float pu = 0.f, pd = 0.f;
            #pragma unroll
            for (int j = 0; j < 2; j++) {
                int lc = wc * 32 + j * 16 + m_lane;
                float a = acc[i][j][r];
                if (hu) {
                    float xu = (lrow < 63) ? bf2f(Xs[(lrow + 1) * 136 + lc])
                                           : bf2f(A[(size_t)(row + 1) * K + bn + lc]);
                    pu += a * xu;
                }
                if (hd) {
                    float xd = (lrow > 0) ? bf2f(Xs[(lrow - 1) * 136 + lc])
                                          : bf2f(A[(size_t)(row - 1) * K + bn + lc]);
                    pd += a * xd;
                }
            }
            #pragma unroll
            for (int off = 1; off < 16; off <<= 1) {
                pu += __shfl_xor(pu, off, 64);
                pd += __shfl_xor(pd, off, 64);
            }
            if (m_lane == 0) {
                atomicAdd(&ydu[row], pu);
                atomicAdd(&ydd[row], pd);
            }
        }
    }
}

// ---- fused banded softmax + f64 prefix scan --------------------------------
__global__ void softmax_prefix(const float* __restrict__ ydu, const float* __restrict__ ydd,
                               const float* __restrict__ au, const float* __restrict__ av,
                               const float* __restrict__ c0p, const int* __restrict__ eos,
                               float* __restrict__ Pup, float* __restrict__ Pdn,
                               float* __restrict__ bg, double* __restrict__ C) {
    __shared__ float pdsh[1024];
    __shared__ double wsum[16];
    int b = blockIdx.x;
    int t = threadIdx.x;           // 0..1023 = row s
    int r = b * S_ + t;
    float c0 = *c0p;
    const float inv_d = 1.0f / D_;
    bool mu = false, md = false;
    float su = 0.f, sd = 0.f;
    if (t < S_ - 1) {
        mu = eos[(size_t)b * S_ * S_ + (size_t)t * S_ + (t + 1)] != 0;
        su = (ydu[r] + av[r] + au[r + 1] + c0) * inv_d;
    }
    if (t > 0) {
        md = eos[(size_t)b * S_ * S_ + (size_t)t * S_ + (t - 1)] != 0;
        sd = (ydd[r] + av[r] + au[r - 1] + c0) * inv_d;
    }
    float pu, pd, pb;
    if (mu && md) {
        float m = fmaxf(su, sd);
        float eu = expf(su - m), ed = expf(sd - m);
        float inv = 1.0f / (eu + ed);
        pu = eu * inv; pd = ed * inv; pb = 0.f;
    } else if (mu) { pu = 1.f; pd = 0.f; pb = 0.f; }
    else if (md)   { pu = 0.f; pd = 1.f; pb = 0.f; }
    else           { pu = pd = pb = 1.0f / S_; }
    Pup[r] = pu; Pdn[r] = pd; bg[r] = pb;
    pdsh[t] = pd;
    __syncthreads();
    double l = 0.0;
    if (t < S_ - 1) {
        float p = sqrtf(pu * pdsh[t + 1] + 1e-9f) + 1e-9f;
        l = log((double)p);
    }
    int lane = t & 63, w = t >> 6;
    double vv = l;
    #pragma unroll
    for (int off = 1; off < 64; off <<= 1) {
        double o = __shfl_up(vv, off, 64);
        if (lane >= off) vv += o;
    }
    if (lane == 63) wsum[w] = vv;
    __syncthreads();
    if (t == 0) {
        double acc = 0.0;
        #pragma unroll
        for (int i = 0; i < 16; i++) { double x = wsum[i]; wsum[i] = acc; acc += x; }
    }
    __syncthreads();
    vv += wsum[w];
    size_t base = (size_t)b * S_;
    if (t == 0) C[base] = 0.0;
    if (t < S_ - 1) C[base + t + 1] = vv;
}

// ---- final outputs: g and neibor -------------------------------------------
__global__ void write_out(const float* __restrict__ Pup, const float* __restrict__ Pdn,
                          const float* __restrict__ bg, const double* __restrict__ C,
                          float* __restrict__ out) {
    int r = blockIdx.x;
    int b = r >> 10, s = r & (S_ - 1);
    size_t rowbase = (size_t)r * S_;
    size_t bb = (size_t)b * S_;
    float pu_s = (s < S_ - 1) ? Pup[r] : 0.f;
    float pd_s = (s > 0) ? Pdn[r] : 0.f;
    float bg_s = bg[r];
    double C_s = C[r];
    int t0 = threadIdx.x * 4;
    float* gp = out;
    float* np = out + (size_t)B_ * S_ * S_;
    float4 bgv = *(const float4*)(bg + bb + t0);
    float4 gv, nv;
    #pragma unroll
    for (int j = 0; j < 4; j++) {
        int t = t0 + j;
        float P_st = (t == s + 1) ? pu_s : ((t == s - 1) ? pd_s : bg_s);
        float P_ts;
        if (t == s - 1)      P_ts = Pup[bb + t];
        else if (t == s + 1) P_ts = Pdn[bb + t];
        else                 P_ts = ((const float*)&bgv)[j];
        float neib = sqrtf(P_st * P_ts + 1e-9f);
        float g;
        if (t == s) {
            g = neib;
        } else {
            double diff = (t > s) ? (C[bb + t] - C_s) : (C_s - C[bb + t]);
            g = expf((float)diff) + 1e-9f;
        }
        ((float*)&gv)[j] = g;
        ((float*)&nv)[j] = neib;
    }
    *(float4*)(gp + rowbase + t0) = gv;
    *(float4*)(np + rowbase + t0) = nv;
}

// ---- launcher ---------------------------------------------------------------
extern "C" void kernel_launch(void* const* d_in, const int* in_sizes, int n_in,
                              void* d_out, int out_size, void* d_ws, size_t ws_size,
                              hipStream_t stream) {
    const float* ctx  = (const float*)d_in[0];
    const int*   eos  = (const int*)d_in[1];
    const float* Wq   = (const float*)d_in[2];
    const float* bq   = (const float*)d_in[3];
    const float* Wk   = (const float*)d_in[4];
    const float* bk   = (const float*)d_in[5];
    const float* ln_a = (const float*)d_in[6];
    const float* ln_b = (const float*)d_in[7];
    float* out = (float*)d_out;

    char* ws = (char*)d_ws;
    size_t off = 0;
    auto alloc = [&](size_t bytes) {
        void* p = ws + off;
        off += (bytes + 255) & ~(size_t)255;
        return p;
    };
    unsigned short* Xb  = (unsigned short*)alloc((size_t)BS * D_ * 2);
    unsigned short* Wqt = (unsigned short*)alloc((size_t)D_ * D_ * 2);
    unsigned short* Wkt = (unsigned short*)alloc((size_t)D_ * D_ * 2);
    unsigned short* Mt  = (unsigned short*)alloc((size_t)D_ * D_ * 2);
    // ---- zeroed region (contiguous): ydu, ydd, u, v, c0 ----
    float*  ydu = (float*)alloc(BS * 4);
    float*  ydd = (float*)alloc(BS * 4);
    float*  u   = (float*)alloc(D_ * 4);
    float*  v   = (float*)alloc(D_ * 4);
    float*  c0  = (float*)alloc(4);
    size_t zero_bytes = (size_t)((char*)c0 - (char*)ydu) + 256;
    // ---- rest (written, not accumulated) ----
    float*  au  = (float*)alloc(BS * 4);
    float*  av  = (float*)alloc(BS * 4);
    float*  Pup = (float*)alloc(BS * 4);
    float*  Pdn = (float*)alloc(BS * 4);
    float*  bg  = (float*)alloc(BS * 4);
    double* Cp  = (double*)alloc(BS * 8);

    // 0. zero the atomic-accumulate targets
    hipMemsetAsync(ydu, 0, zero_bytes, stream);
    // 1. prep: transpose Wq/Wk -> bf16, bias terms u, v, c0
    prep_kernel<<<2056, 256, 0, stream>>>(Wq, Wk, bq, bk, Wqt, Wkt, u, v, c0);
    // 2. LayerNorm -> bf16 (+ au, av)
    ln_kernel<<<BS, 256, 0, stream>>>(ctx, ln_a, ln_b, u, v, Xb, au, av);
    // 3. Mt[n][k] = sum_d Wk[d][n] Wq[d][k]
    gemm_bt64<<<dim3(16, 16), 256, 0, stream>>>(Wkt, Wqt, Mt, D_, D_, D_);
    // 4. fused: Y = Xb Mt^T (registers only) + banded dots, XCD-swizzled grid
    gemm_fused<<<1024, 256, 0, stream>>>(Xb, Mt, ydu, ydd, BS, D_, D_);
    // 5. fused banded softmax + prefix scan
    softmax_prefix<<<B_, 1024, 0, stream>>>(ydu, ydd, au, av, c0, eos, Pup, Pdn, bg, Cp);
    // 6. outputs
    write_out<<<BS, 256, 0, stream>>>(Pup, Pdn, bg, Cp, out);
}